// Round 15
// baseline (48.482 us; speedup 1.0000x reference)
//
#include <hip/hip_runtime.h>

// Problem constants: B=256, P=64, D=1024, MARGIN=0.1
constexpr int NB = 256;
constexpr int NP = 64;
constexpr int ND = 1024;
constexpr float MARGIN = 0.1f;

typedef __attribute__((ext_vector_type(8))) short bf16x8;    // 8 bf16 (4 VGPRs)
typedef __attribute__((ext_vector_type(4))) short bf16x4;    // 4 bf16 (2 VGPRs)
typedef __attribute__((ext_vector_type(16))) float f32x16;   // 32x32 MFMA acc

// fp32 -> bf16 round-to-nearest-even (inputs are finite gaussians; no NaN path)
static __device__ inline unsigned short f2bf(float f) {
  unsigned u = __builtin_bit_cast(unsigned, f);
  u += 0x7fffu + ((u >> 16) & 1u);
  return (unsigned short)(u >> 16);
}

static __device__ inline bf16x4 cvt4(float4 a) {
  bf16x4 r;
  r[0] = (short)f2bf(a.x); r[1] = (short)f2bf(a.y);
  r[2] = (short)f2bf(a.z); r[3] = (short)f2bf(a.w);
  return r;
}

// ---------------------------------------------------------------------------
// Kernel 0: disFtr fp32 -> bf16, once. (No ticket — R8-R14 fusion arc netted
// zero; reverted to plain 4-kernel pipeline.)
// ---------------------------------------------------------------------------
__global__ __launch_bounds__(256) void cvtB_kernel(
    const float* __restrict__ src, short* __restrict__ dst) {
  const int idx = (blockIdx.x * 256 + threadIdx.x) * 4;
  float4 v = *reinterpret_cast<const float4*>(src + idx);
  *reinterpret_cast<bf16x4*>(dst + idx) = cvt4(v);
}

// ---------------------------------------------------------------------------
// Kernel 1 (R15): simMax via 32x32x16 MFMA — halves ds_read per FLOP.
// R14 arithmetic: R7's k-loop = 2048 ds_read_b128/CU (~10us LDS pipe) for
// 2048 MFMA(16x16x32); the 32x32x16 shape does the same FLOPs with 1024
// reads + 1024 MFMAs. Everything else (A chunk staging, XOR swizzle, B
// rolling register window, 1 barrier/chunk) is R7-proven and unchanged.
// grid=256 (1 block/CU), 1024 threads = 16 waves = 2 p-halves x 8 c-groups;
// wave owns one 32p x 32c tile, acc = f32x16.
// Frag layout: A lane l -> row=ph*32+(l&31), k=(l>>5)*8+j (symmetric to the
// R2-proven 16x16 pattern); B identical on disB rows (B^T input).
// D: col=l&31 (m74-verified); 16 regs x 2 lane-halves cover all 32 rows ->
// row max = fmax over regs + shfl_xor(32). p-halves combined via LDS.
// ---------------------------------------------------------------------------
__global__ __launch_bounds__(1024, 4) void simmax_kernel(
    const float* __restrict__ imFtr, const short* __restrict__ disB,
    float* __restrict__ simMax) {
  const int i  = blockIdx.x;
  const int t  = threadIdx.x;
  const int w  = t >> 6;   // wave 0..15
  const int l  = t & 63;
  const int lc = l & 31;   // col within tile / A row within p-tile
  const int hi = l >> 5;   // k-half 0..1
  const int ph = w >> 3;   // p-half 0..1
  const int cg = w & 7;    // col-group 0..7

  __shared__ short Asl[2][NP][256];  // 64 KB: double-buffered A k-chunk (bf16)
  __shared__ float Red[8][32];       // p-half combine

  f32x16 acc;
#pragma unroll
  for (int r = 0; r < 16; ++r) acc[r] = 0.0f;

  // --- A staging mapping (R7 verbatim): thread t -> row ar, col-group aj ---
  const int ar = t >> 4;
  const int aj = t & 15;
  const float* abase = imFtr + ((size_t)i * NP + ar) * ND + aj * 4;
  float4 areg[4];

#define STAGE_LOAD(C)                                                        \
  _Pragma("unroll")                                                          \
  for (int g = 0; g < 4; ++g)                                                \
    areg[g] = *reinterpret_cast<const float4*>(abase + (C) * 256 + g * 64);

#define STAGE_WRITE(BUF)                                                     \
  _Pragma("unroll")                                                          \
  for (int g = 0; g < 4; ++g) {                                              \
    const int s  = g * 8 + (aj >> 1);                                        \
    const int so = (s ^ (ar & 15)) * 8 + (aj & 1) * 4;                       \
    *reinterpret_cast<bf16x4*>(&Asl[BUF][ar][so]) = cvt4(areg[g]);           \
  }

  // --- B: wave cols cg*32+lc, lane k-offset hi*8; rolling 8-deep window ---
  const short* bp = disB + (size_t)(cg * 32 + lc) * ND + hi * 8;
  bf16x8 breg[8];

  const int row = ph * 32 + lc;   // A row this lane reads
  const int r15 = row & 15;

  // ---- prologue: A chunk 0 + B window for k-iters 0..7 ----
  STAGE_LOAD(0);
#pragma unroll
  for (int j = 0; j < 8; ++j)
    breg[j] = *reinterpret_cast<const bf16x8*>(bp + j * 16);
  STAGE_WRITE(0);
  __syncthreads();

#pragma unroll
  for (int c = 0; c < 4; ++c) {
    const int cb = c & 1;
    if (c < 3) STAGE_LOAD(c + 1);  // next A chunk: ~full chunk of lead
#pragma unroll
    for (int j8 = 0; j8 < 16; ++j8) {     // 16 k-iters of 16 per chunk
      const int jj = c * 16 + j8;         // global k-iter (compile-time)
      const int so = ((j8 * 2 + hi) ^ r15) * 8;
      bf16x8 a = *reinterpret_cast<const bf16x8*>(&Asl[cb][row][so]);
      acc = __builtin_amdgcn_mfma_f32_32x32x16_bf16(a, breg[jj & 7], acc, 0, 0, 0);
      if (jj + 8 < 64)                    // refill window 8 iters ahead
        breg[jj & 7] = *reinterpret_cast<const bf16x8*>(bp + (jj + 8) * 16);
    }
    if (c < 3) {
      STAGE_WRITE(cb ^ 1);  // other buffer; readers synced at prior barrier
      __syncthreads();
    }
  }

#undef STAGE_LOAD
#undef STAGE_WRITE

  // ---- max over this wave's 32 p-rows for col cg*32+lc ----
  float m = acc[0];
#pragma unroll
  for (int r = 1; r < 16; ++r) m = fmaxf(m, acc[r]);
  m = fmaxf(m, __shfl_xor(m, 32));   // combine the two lane-half row sets

  // ---- combine p-halves across waves (ph0 writes, ph1 maxes+stores) ----
  if (ph == 0 && l < 32) Red[cg][lc] = m;
  __syncthreads();
  if (ph == 1 && l < 32)
    simMax[(size_t)i * NB + cg * 32 + lc] = fmaxf(m, Red[cg][lc]);
}

// ---------------------------------------------------------------------------
// Kernel 2: per-row partial sums {mask count, loss_it, loss_ti}. (R7 proven)
// ---------------------------------------------------------------------------
__global__ __launch_bounds__(256) void loss_kernel(
    const float* __restrict__ simMax, const int* __restrict__ lbl,
    float* __restrict__ partial) {
  const int i = blockIdx.x;
  const int j = threadIdx.x;
  __shared__ float posi_sh;
  __shared__ float red[3][4];

  float s = simMax[(size_t)i * NB + j];
  if (j == i) posi_sh = s;
  __syncthreads();
  const float posi = posi_sh;
  const float posj = simMax[(size_t)j * NB + j];

  const float msk = (lbl[i] != lbl[j]) ? 1.0f : 0.0f;
  float c  = msk;
  float l1 = msk * fmaxf(s - posi + MARGIN, 0.0f);
  float l2 = msk * fmaxf(s - posj + MARGIN, 0.0f);
#pragma unroll
  for (int o = 32; o > 0; o >>= 1) {
    c  += __shfl_down(c, o);
    l1 += __shfl_down(l1, o);
    l2 += __shfl_down(l2, o);
  }
  const int w = j >> 6;
  if ((j & 63) == 0) { red[0][w] = c; red[1][w] = l1; red[2][w] = l2; }
  __syncthreads();
  if (j == 0) {
    partial[i * 3 + 0] = red[0][0] + red[0][1] + red[0][2] + red[0][3];
    partial[i * 3 + 1] = red[1][0] + red[1][1] + red[1][2] + red[1][3];
    partial[i * 3 + 2] = red[2][0] + red[2][1] + red[2][2] + red[2][3];
  }
}

// ---------------------------------------------------------------------------
// Kernel 3: final reduction over 256 row-partials -> loss scalar. (R7 proven)
// ---------------------------------------------------------------------------
__global__ __launch_bounds__(256) void finalize_kernel(
    const float* __restrict__ partial, float* __restrict__ out) {
  const int t = threadIdx.x;
  __shared__ float red[3][4];
  float c  = partial[t * 3 + 0];
  float l1 = partial[t * 3 + 1];
  float l2 = partial[t * 3 + 2];
#pragma unroll
  for (int o = 32; o > 0; o >>= 1) {
    c  += __shfl_down(c, o);
    l1 += __shfl_down(l1, o);
    l2 += __shfl_down(l2, o);
  }
  const int w = t >> 6;
  if ((t & 63) == 0) { red[0][w] = c; red[1][w] = l1; red[2][w] = l2; }
  __syncthreads();
  if (t == 0) {
    float cs  = red[0][0] + red[0][1] + red[0][2] + red[0][3];
    float l1s = red[1][0] + red[1][1] + red[1][2] + red[1][3];
    float l2s = red[2][0] + red[2][1] + red[2][2] + red[2][3];
    float loss = l1s / cs;                   // reference divides unconditionally
    loss += (cs > 0.0f) ? (l2s / cs) : 0.0f; // guarded second term, as in ref
    out[0] = loss;
  }
}

extern "C" void kernel_launch(void* const* d_in, const int* in_sizes, int n_in,
                              void* d_out, int out_size, void* d_ws, size_t ws_size,
                              hipStream_t stream) {
  (void)in_sizes; (void)n_in; (void)out_size; (void)ws_size;
  const float* imFtr  = (const float*)d_in[0];
  const float* disFtr = (const float*)d_in[1];
  const int*   lbl    = (const int*)d_in[2];
  float* out = (float*)d_out;

  const size_t disB_bytes = (size_t)NB * ND * sizeof(short);      // 512 KB
  const size_t sim_bytes  = (size_t)NB * NB * sizeof(float);      // 256 KB

  short* disB    = (short*)d_ws;
  float* simMax  = (float*)((char*)d_ws + disB_bytes);
  float* partial = (float*)((char*)d_ws + disB_bytes + sim_bytes);

  cvtB_kernel<<<dim3(NB), dim3(256), 0, stream>>>(disFtr, disB);
  simmax_kernel<<<dim3(NB), dim3(1024), 0, stream>>>(imFtr, disB, simMax);
  loss_kernel<<<dim3(NB), dim3(256), 0, stream>>>(simMax, lbl, partial);
  finalize_kernel<<<dim3(1), dim3(256), 0, stream>>>(partial, out);
}